// Round 4
// baseline (245.127 us; speedup 1.0000x reference)
//
#include <hip/hip_runtime.h>
#include <hip/hip_bf16.h>
#include <math.h>

// PAM fused attention, round 4: split-K flash decoding (4 chunks -> 8 blocks/CU,
// 100% occupancy). Fixed -46 softmax shift makes partials exactly additive.
// B=4, Cm=6, C=64, N=4096.

#define BATCH 4
#define CMAP  6
#define CH    64
#define NSP   4096
#define TM    32        // query rows per block
#define TN    64        // key cols per tile
#define SPLIT 4         // key-range chunks (flash-decoding)
#define MCHUNK (NSP/SPLIT)   // 1024 keys per chunk, 16 tiles
#define PSTR  72        // p_lds row stride (bf16): b128 reads hit the 8-phase minimum

typedef __attribute__((ext_vector_type(8))) short short8;
typedef __attribute__((ext_vector_type(4))) float f32x4;

__device__ __forceinline__ unsigned f2bf(float f) {      // RNE f32->bf16 bits
    unsigned u = __float_as_uint(f);
    return (u + 0x7fffu + ((u >> 16) & 1u)) >> 16;
}

#define INVLN2 1.44269504088896f
#define SHIFT_BF16 0xC238u   /* bf16(-46.0): fixed softmax shift (exact, cancels) */
#define ONE_BF16   0x3F80u

// ---------------- kernel 1: all projections fused ----------------
// grid (NSP/64, 2, BATCH), block 256. Each wave: 8 output channels.
__global__ void proj_kernel(const float* __restrict__ map1, const float* __restrict__ map2,
                            const float* __restrict__ fm,
                            const float* __restrict__ wb, const float* __restrict__ bb,
                            const float* __restrict__ wc, const float* __restrict__ bc,
                            const float* __restrict__ wd, const float* __restrict__ bd,
                            unsigned short* __restrict__ featq8,
                            unsigned short* __restrict__ featk8,
                            unsigned short* __restrict__ featd)
{
    const int b    = blockIdx.z;
    const int half = blockIdx.y;
    const int n    = blockIdx.x * 64 + (threadIdx.x & 63);
    const int og   = threadIdx.x >> 6;

    // ---- V projection: 8 channels per wave
    float vals[CH];
#pragma unroll
    for (int c = 0; c < CH; ++c)
        vals[c] = fm[(size_t)(b*CH + c)*NSP + n];
#pragma unroll
    for (int oi = 0; oi < 8; ++oi) {
        const int o = half*32 + og*8 + oi;
        float a = bd[o];
#pragma unroll
        for (int c = 0; c < CH; ++c)
            a = fmaf(vals[c], wd[o*CH + c], a);
        featd[(size_t)(b*CH + o)*NSP + n] = (unsigned short)f2bf(a);
    }

    // ---- Q/K fragment rows (one wave per (x,b))
    if (half == 0 && og == 0) {
        float v1[CMAP], v2[CMAP];
#pragma unroll
        for (int c = 0; c < CMAP; ++c) {
            v1[c] = map1[(size_t)(b*CMAP + c)*NSP + n];
            v2[c] = map2[(size_t)(b*CMAP + c)*NSP + n];
        }
        unsigned qv[CMAP], kv[CMAP];
#pragma unroll
        for (int o = 0; o < CMAP; ++o) {
            float a1 = bb[o], a2 = bc[o];
#pragma unroll
            for (int c = 0; c < CMAP; ++c) {
                a1 = fmaf(v1[c], wb[o*CMAP + c], a1);
                a2 = fmaf(v2[c], wc[o*CMAP + c], a2);
            }
            qv[o] = f2bf(a1 * INVLN2);
            kv[o] = f2bf(a2);
        }
        uint4 qw, kw;
        qw.x = qv[0] | (qv[1] << 16);
        qw.y = qv[2] | (qv[3] << 16);
        qw.z = qv[4] | (qv[5] << 16);
        qw.w = SHIFT_BF16;                       // slot6 = -46, slot7 = 0
        kw.x = kv[0] | (kv[1] << 16);
        kw.y = kv[2] | (kv[3] << 16);
        kw.z = kv[4] | (kv[5] << 16);
        kw.w = ONE_BF16;                         // slot6 = 1, slot7 = 0
        *(uint4*)&featq8[(size_t)(b*NSP + n)*8] = qw;
        *(uint4*)&featk8[(size_t)(b*NSP + n)*8] = kw;
    }
}

// ---------------- kernel 2: split-K attention, all-MFMA ----------------
// grid (NSP/TM=128, SPLIT, BATCH) = 2048 blocks -> 8 blocks/CU. LDS ~9.8 KB.
__global__ __launch_bounds__(256, 8)
void attn_kernel(const unsigned short* __restrict__ featq8,
                 const unsigned short* __restrict__ featk8,
                 const unsigned short* __restrict__ featd,
                 float* __restrict__ pacc, float* __restrict__ pl)
{
    __shared__ unsigned short p_lds[2][TM*PSTR];
    __shared__ float l_part[4][TM];
    __shared__ float l_final[TM];

    const int b     = blockIdx.z;
    const int chunk = blockIdx.y;
    const int n0    = blockIdx.x * TM;
    const int m0c   = chunk * MCHUNK;
    const int t     = threadIdx.x;
    const int lane  = t & 63, w = t >> 6;
    const int row16 = lane & 15, quad = lane >> 4;
    const int rb = w >> 1;                         // PV: query row-block (0/1)
    const int cs = w & 1;                          // PV: 32-channel slice

    // Q B-frags: B[k=quad*8+j][q=row16]; only quad0 holds real k
    short8 qf0 = {0,0,0,0,0,0,0,0}, qf1 = {0,0,0,0,0,0,0,0};
    if (quad == 0) {
        qf0 = *(const short8*)&featq8[(size_t)(b*NSP + n0 + row16)*8];
        qf1 = *(const short8*)&featq8[(size_t)(b*NSP + n0 + 16 + row16)*8];
    }
    // K A-frag stream: A[m=row16][k=quad*8+j]; wave w owns m-block w
    const unsigned short* kfp = featk8 + (size_t)(b*NSP + m0c + w*16 + row16)*8;
    // V B-frag stream: B[k=quad*8+j -> m][ch=cs*32(+16)+row16]
    const unsigned short* vb0 = featd + (size_t)(b*CH + cs*32 + row16)*NSP + m0c + quad*8;
    const unsigned short* vb1 = vb0 + 16*NSP;

    short8 kf = {0,0,0,0,0,0,0,0};
    if (quad == 0) kf = *(const short8*)kfp;
    short8 v00 = *(const short8*)(vb0);
    short8 v01 = *(const short8*)(vb0 + 32);
    short8 v10 = *(const short8*)(vb1);
    short8 v11 = *(const short8*)(vb1 + 32);

    const f32x4 zf = {0.f,0.f,0.f,0.f};
    f32x4 acc0 = zf, acc1 = zf;
    float l0 = 0.f, l1 = 0.f;
    short8 kf_n = {0,0,0,0,0,0,0,0};

    for (int tile = 0; tile < MCHUNK/TN; ++tile) {
        // ---- scores: S^T[m][q] = K·Q^T (k6 slot adds the -46 shift)
        f32x4 s0 = __builtin_amdgcn_mfma_f32_16x16x32_bf16(kf, qf0, zf, 0, 0, 0);
        f32x4 s1 = __builtin_amdgcn_mfma_f32_16x16x32_bf16(kf, qf1, zf, 0, 0, 0);

        // ---- prefetch next tile's K/V frags (wraps; overlaps exp/pack)
        const int m1 = ((tile + 1) & (MCHUNK/TN - 1)) * TN;
        if (quad == 0) kf_n = *(const short8*)(kfp + (size_t)m1*8);
        const short8 v00n = *(const short8*)(vb0 + m1);
        const short8 v01n = *(const short8*)(vb0 + m1 + 32);
        const short8 v10n = *(const short8*)(vb1 + m1);
        const short8 v11n = *(const short8*)(vb1 + m1 + 32);

        // ---- p = exp2(s); C-layout: col=row16=q, row=quad*4+r = m-offset
        {
            const float p0 = exp2f(s0[0]), p1 = exp2f(s0[1]);
            const float p2 = exp2f(s0[2]), p3 = exp2f(s0[3]);
            l0 += (p0 + p1) + (p2 + p3);
            uint2 pw;
            pw.x = __builtin_amdgcn_perm(__float_as_uint(p1), __float_as_uint(p0), 0x07060302u);
            pw.y = __builtin_amdgcn_perm(__float_as_uint(p3), __float_as_uint(p2), 0x07060302u);
            *(uint2*)&p_lds[tile & 1][row16*PSTR + w*16 + quad*4] = pw;
        }
        {
            const float p0 = exp2f(s1[0]), p1 = exp2f(s1[1]);
            const float p2 = exp2f(s1[2]), p3 = exp2f(s1[3]);
            l1 += (p0 + p1) + (p2 + p3);
            uint2 pw;
            pw.x = __builtin_amdgcn_perm(__float_as_uint(p1), __float_as_uint(p0), 0x07060302u);
            pw.y = __builtin_amdgcn_perm(__float_as_uint(p3), __float_as_uint(p2), 0x07060302u);
            *(uint2*)&p_lds[tile & 1][(16 + row16)*PSTR + w*16 + quad*4] = pw;
        }

        __syncthreads();

        // ---- PV: A[q=row16][k=quad*8+j -> m]
        const unsigned short* pr = &p_lds[tile & 1][(rb*16 + row16)*PSTR + quad*8];
        const short8 a0 = *(const short8*)pr;
        const short8 a1 = *(const short8*)(pr + 32);
        acc0 = __builtin_amdgcn_mfma_f32_16x16x32_bf16(a0, v00, acc0, 0, 0, 0);
        acc0 = __builtin_amdgcn_mfma_f32_16x16x32_bf16(a1, v01, acc0, 0, 0, 0);
        acc1 = __builtin_amdgcn_mfma_f32_16x16x32_bf16(a0, v10, acc1, 0, 0, 0);
        acc1 = __builtin_amdgcn_mfma_f32_16x16x32_bf16(a1, v11, acc1, 0, 0, 0);

        kf = kf_n; v00 = v00n; v01 = v01n; v10 = v10n; v11 = v11n;
    }

    // ---- partial l: sum over quads, then waves
    l0 += __shfl_xor(l0, 16); l0 += __shfl_xor(l0, 32);
    l1 += __shfl_xor(l1, 16); l1 += __shfl_xor(l1, 32);
    if (quad == 0) { l_part[w][row16] = l0; l_part[w][16 + row16] = l1; }
    __syncthreads();
    if (t < TM) {
        const float lf = (l_part[0][t] + l_part[1][t]) + (l_part[2][t] + l_part[3][t]);
        pl[(size_t)(chunk*BATCH + b)*NSP + n0 + t] = lf;
    }

    // ---- partial acc: D layout col=row16=ch-offset, row=quad*4+reg=query-offset
#pragma unroll
    for (int nb = 0; nb < 2; ++nb) {
        const int ch = cs*32 + nb*16 + row16;
        const size_t base = ((size_t)((chunk*BATCH + b)*CH + ch))*NSP + n0 + rb*16 + quad*4;
        const f32x4 a = nb ? acc1 : acc0;
        float4 o; o.x = a[0]; o.y = a[1]; o.z = a[2]; o.w = a[3];
        *(float4*)&pacc[base] = o;
    }
}

// ---------------- kernel 3: combine partials + epilogue ----------------
// grid 1024, block 256; one float4 of out per thread.
__global__ void reduce_kernel(const float* __restrict__ pacc, const float* __restrict__ pl,
                              const float* __restrict__ fm, const float* __restrict__ alpha_p,
                              float* __restrict__ out)
{
    const size_t i = ((size_t)blockIdx.x * 256 + threadIdx.x) * 4;   // [b][ch][n] flat
    const int b = (int)(i >> 18);                 // CH*NSP = 2^18
    const int n = (int)(i & (NSP - 1));
    const size_t STRIDE = (size_t)BATCH*CH*NSP;

    float4 a = *(const float4*)&pacc[i];
    float4 l = *(const float4*)&pl[(size_t)b*NSP + n];
#pragma unroll
    for (int c = 1; c < SPLIT; ++c) {
        const float4 ac = *(const float4*)&pacc[i + c*STRIDE];
        const float4 lc = *(const float4*)&pl[(size_t)(c*BATCH + b)*NSP + n];
        a.x += ac.x; a.y += ac.y; a.z += ac.z; a.w += ac.w;
        l.x += lc.x; l.y += lc.y; l.z += lc.z; l.w += lc.w;
    }
    const float alpha = alpha_p[0];
    const float4 f = *(const float4*)&fm[i];
    float4 o;
    o.x = fmaf(alpha / (l.x + 1e-30f), a.x, f.x);
    o.y = fmaf(alpha / (l.y + 1e-30f), a.y, f.y);
    o.z = fmaf(alpha / (l.z + 1e-30f), a.z, f.z);
    o.w = fmaf(alpha / (l.w + 1e-30f), a.w, f.w);
    *(float4*)&out[i] = o;
}

// ---------------- launcher ----------------
extern "C" void kernel_launch(void* const* d_in, const int* in_sizes, int n_in,
                              void* d_out, int out_size, void* d_ws, size_t ws_size,
                              hipStream_t stream)
{
    const float* map1  = (const float*)d_in[0];
    const float* map2  = (const float*)d_in[1];
    const float* fm    = (const float*)d_in[2];
    const float* wb    = (const float*)d_in[3];
    const float* bb    = (const float*)d_in[4];
    const float* wc    = (const float*)d_in[5];
    const float* bc    = (const float*)d_in[6];
    const float* wd    = (const float*)d_in[7];
    const float* bd    = (const float*)d_in[8];
    const float* alpha = (const float*)d_in[9];
    float* out = (float*)d_out;

    // ws: featq8 256KB | featk8 256KB | featd 2MB | pl 256KB | pacc 16MB  (~19MB)
    unsigned short* featq8 = (unsigned short*)d_ws;
    unsigned short* featk8 = featq8 + (size_t)BATCH*NSP*8;
    unsigned short* featd  = featk8 + (size_t)BATCH*NSP*8;
    float*          pl     = (float*)(featd + (size_t)BATCH*CH*NSP);
    float*          pacc   = pl + (size_t)SPLIT*BATCH*NSP;

    proj_kernel<<<dim3(NSP/64, 2, BATCH), 256, 0, stream>>>(
        map1, map2, fm, wb, bb, wc, bc, wd, bd, featq8, featk8, featd);
    attn_kernel<<<dim3(NSP/TM, SPLIT, BATCH), 256, 0, stream>>>(
        featq8, featk8, featd, pacc, pl);
    reduce_kernel<<<dim3((BATCH*CH*NSP/4)/256), 256, 0, stream>>>(
        pacc, pl, fm, alpha, out);
}

// Round 5
// 157.742 us; speedup vs baseline: 1.5540x; 1.5540x over previous
//
#include <hip/hip_runtime.h>
#include <hip/hip_bf16.h>
#include <math.h>

// PAM fused attention, round 5: R3 structure + channel-split grid doubling.
// Key lesson from R4: never split the reuse (key) dimension across blocks —
// split the redundant (channel) dimension instead; V-stream L2 lockstep reuse
// is preserved and no partial/reduce round-trip is needed.
// B=4, Cm=6, C=64, N=4096.

#define BATCH 4
#define CMAP  6
#define CH    64
#define NSP   4096
#define TM    32        // query rows per block
#define TN    64        // key cols per tile
#define PSTR  72        // p_lds row stride (bf16): b128 reads near the 8-phase minimum

typedef __attribute__((ext_vector_type(8))) short short8;
typedef __attribute__((ext_vector_type(4))) float f32x4;

__device__ __forceinline__ unsigned f2bf(float f) {      // RNE f32->bf16 bits
    unsigned u = __float_as_uint(f);
    return (u + 0x7fffu + ((u >> 16) & 1u)) >> 16;
}

#define INVLN2 1.44269504088896f
#define SHIFT_BF16 0xC238u   /* bf16(-46.0): fixed softmax shift (exact, cancels) */
#define ONE_BF16   0x3F80u

// ---------------- kernel 1: all projections fused ----------------
// grid (NSP/64, 2, BATCH), block 256. Each wave: 8 output channels.
__global__ void proj_kernel(const float* __restrict__ map1, const float* __restrict__ map2,
                            const float* __restrict__ fm,
                            const float* __restrict__ wb, const float* __restrict__ bb,
                            const float* __restrict__ wc, const float* __restrict__ bc,
                            const float* __restrict__ wd, const float* __restrict__ bd,
                            unsigned short* __restrict__ featq8,
                            unsigned short* __restrict__ featk8,
                            unsigned short* __restrict__ featd)
{
    const int b    = blockIdx.z;
    const int half = blockIdx.y;
    const int n    = blockIdx.x * 64 + (threadIdx.x & 63);
    const int og   = threadIdx.x >> 6;

    // ---- V projection: 8 channels per wave
    float vals[CH];
#pragma unroll
    for (int c = 0; c < CH; ++c)
        vals[c] = fm[(size_t)(b*CH + c)*NSP + n];
#pragma unroll
    for (int oi = 0; oi < 8; ++oi) {
        const int o = half*32 + og*8 + oi;
        float a = bd[o];
#pragma unroll
        for (int c = 0; c < CH; ++c)
            a = fmaf(vals[c], wd[o*CH + c], a);
        featd[(size_t)(b*CH + o)*NSP + n] = (unsigned short)f2bf(a);
    }

    // ---- Q/K fragment rows (one wave per (x,b))
    if (half == 0 && og == 0) {
        float v1[CMAP], v2[CMAP];
#pragma unroll
        for (int c = 0; c < CMAP; ++c) {
            v1[c] = map1[(size_t)(b*CMAP + c)*NSP + n];
            v2[c] = map2[(size_t)(b*CMAP + c)*NSP + n];
        }
        unsigned qv[CMAP], kv[CMAP];
#pragma unroll
        for (int o = 0; o < CMAP; ++o) {
            float a1 = bb[o], a2 = bc[o];
#pragma unroll
            for (int c = 0; c < CMAP; ++c) {
                a1 = fmaf(v1[c], wb[o*CMAP + c], a1);
                a2 = fmaf(v2[c], wc[o*CMAP + c], a2);
            }
            qv[o] = f2bf(a1 * INVLN2);
            kv[o] = f2bf(a2);
        }
        uint4 qw, kw;
        qw.x = qv[0] | (qv[1] << 16);
        qw.y = qv[2] | (qv[3] << 16);
        qw.z = qv[4] | (qv[5] << 16);
        qw.w = SHIFT_BF16;                       // slot6 = -46, slot7 = 0
        kw.x = kv[0] | (kv[1] << 16);
        kw.y = kv[2] | (kv[3] << 16);
        kw.z = kv[4] | (kv[5] << 16);
        kw.w = ONE_BF16;                         // slot6 = 1, slot7 = 0
        *(uint4*)&featq8[(size_t)(b*NSP + n)*8] = qw;
        *(uint4*)&featk8[(size_t)(b*NSP + n)*8] = kw;
    }
}

// ---------------- kernel 2: fused attention, channel-split ----------------
// grid (NSP/TM=128, 2, BATCH) = 1024 blocks -> 4 blocks/CU, 16 waves/CU.
// Each block: 32 query rows x 32 V-channels, all 4096 keys. LDS ~9.8 KB.
__global__ __launch_bounds__(256, 4)
void attn_kernel(const unsigned short* __restrict__ featq8,
                 const unsigned short* __restrict__ featk8,
                 const unsigned short* __restrict__ featd,
                 const float* __restrict__ fm, const float* __restrict__ alpha_p,
                 float* __restrict__ out)
{
    __shared__ unsigned short p_lds[2][TM*PSTR];   // P^T round-trip, double-buffered
    __shared__ float l_part[4][TM];
    __shared__ float l_final[TM];

    const int b    = blockIdx.z;
    const int chh  = blockIdx.y;                   // 32-channel half
    const int n0   = blockIdx.x * TM;
    const int t    = threadIdx.x;
    const int lane = t & 63, w = t >> 6;
    const int row16 = lane & 15, quad = lane >> 4;
    const int rb = w >> 1;                         // PV: query row-block (0/1)
    const int cs = w & 1;                          // PV: 16-channel slice within half

    // Q B-frags (scores): B[k=quad*8+j][q=row16]; only quad0 holds real k
    short8 qf0 = {0,0,0,0,0,0,0,0}, qf1 = {0,0,0,0,0,0,0,0};
    if (quad == 0) {
        qf0 = *(const short8*)&featq8[(size_t)(b*NSP + n0 + row16)*8];
        qf1 = *(const short8*)&featq8[(size_t)(b*NSP + n0 + 16 + row16)*8];
    }
    // K A-frag stream (scores): A[m=row16][k=quad*8+j]; wave w owns m-block w
    const unsigned short* kfp = featk8 + (size_t)(b*NSP + w*16 + row16)*8;
    // V B-frag stream (PV): B[k=quad*8+j -> m][ch = chh*32 + cs*16 + row16]
    const unsigned short* vbp = featd +
        (size_t)(b*CH + chh*32 + cs*16 + row16)*NSP + quad*8;

    short8 kf = {0,0,0,0,0,0,0,0};
    if (quad == 0) kf = *(const short8*)kfp;
    short8 v0 = *(const short8*)(vbp);
    short8 v1 = *(const short8*)(vbp + 32);

    const f32x4 zf = {0.f,0.f,0.f,0.f};
    f32x4 acc = zf;
    float l0 = 0.f, l1 = 0.f;
    short8 kf_n = {0,0,0,0,0,0,0,0};

    for (int tile = 0; tile < NSP/TN; ++tile) {
        // ---- scores: S^T[m][q] = K·Q^T (k6 slot adds the -46 shift)
        f32x4 s0 = __builtin_amdgcn_mfma_f32_16x16x32_bf16(kf, qf0, zf, 0, 0, 0);
        f32x4 s1 = __builtin_amdgcn_mfma_f32_16x16x32_bf16(kf, qf1, zf, 0, 0, 0);

        // ---- prefetch next tile's K/V frags (wraps; overlaps exp/pack)
        const int m1 = ((tile + 1) & (NSP/TN - 1)) * TN;
        if (quad == 0) kf_n = *(const short8*)(kfp + (size_t)m1*8);
        const short8 v0n = *(const short8*)(vbp + m1);
        const short8 v1n = *(const short8*)(vbp + m1 + 32);

        // ---- p = exp2(s); C-layout: col=row16=q, row=quad*4+r = m-offset
        {
            const float p0 = exp2f(s0[0]), p1 = exp2f(s0[1]);
            const float p2 = exp2f(s0[2]), p3 = exp2f(s0[3]);
            l0 += (p0 + p1) + (p2 + p3);
            uint2 pw;   // truncate-to-bf16 pack
            pw.x = __builtin_amdgcn_perm(__float_as_uint(p1), __float_as_uint(p0), 0x07060302u);
            pw.y = __builtin_amdgcn_perm(__float_as_uint(p3), __float_as_uint(p2), 0x07060302u);
            *(uint2*)&p_lds[tile & 1][row16*PSTR + w*16 + quad*4] = pw;
        }
        {
            const float p0 = exp2f(s1[0]), p1 = exp2f(s1[1]);
            const float p2 = exp2f(s1[2]), p3 = exp2f(s1[3]);
            l1 += (p0 + p1) + (p2 + p3);
            uint2 pw;
            pw.x = __builtin_amdgcn_perm(__float_as_uint(p1), __float_as_uint(p0), 0x07060302u);
            pw.y = __builtin_amdgcn_perm(__float_as_uint(p3), __float_as_uint(p2), 0x07060302u);
            *(uint2*)&p_lds[tile & 1][(16 + row16)*PSTR + w*16 + quad*4] = pw;
        }

        __syncthreads();   // P complete (double buffer -> one barrier per tile)

        // ---- PV: A[q=row16][k=quad*8+j -> m], wave covers q-rows rb*16..+15
        const unsigned short* pr = &p_lds[tile & 1][(rb*16 + row16)*PSTR + quad*8];
        const short8 a0 = *(const short8*)pr;          // m = 0..31 of this tile
        const short8 a1 = *(const short8*)(pr + 32);   // m = 32..63
        acc = __builtin_amdgcn_mfma_f32_16x16x32_bf16(a0, v0, acc, 0, 0, 0);
        acc = __builtin_amdgcn_mfma_f32_16x16x32_bf16(a1, v1, acc, 0, 0, 0);

        kf = kf_n; v0 = v0n; v1 = v1n;
    }

    // ---- l: sum over quads (m sub-blocks), then over waves (m blocks)
    l0 += __shfl_xor(l0, 16); l0 += __shfl_xor(l0, 32);
    l1 += __shfl_xor(l1, 16); l1 += __shfl_xor(l1, 32);
    if (quad == 0) { l_part[w][row16] = l0; l_part[w][16 + row16] = l1; }
    __syncthreads();
    if (t < TM)
        l_final[t] = (l_part[0][t] + l_part[1][t]) + (l_part[2][t] + l_part[3][t]);
    __syncthreads();

    // ---- epilogue: D layout col=row16=ch-offset, row=quad*4+reg=query-offset
    const float4 lv = *(const float4*)&l_final[rb*16 + quad*4];
    const float alpha = alpha_p[0];
    const float c0 = alpha / (lv.x + 1e-30f);
    const float c1 = alpha / (lv.y + 1e-30f);
    const float c2 = alpha / (lv.z + 1e-30f);
    const float c3 = alpha / (lv.w + 1e-30f);
    {
        const int ch = chh*32 + cs*16 + row16;
        const size_t base = (size_t)(b*CH + ch)*NSP + n0 + rb*16 + quad*4;
        const float4 f = *(const float4*)&fm[base];
        float4 o;
        o.x = fmaf(c0, acc[0], f.x);
        o.y = fmaf(c1, acc[1], f.y);
        o.z = fmaf(c2, acc[2], f.z);
        o.w = fmaf(c3, acc[3], f.w);
        *(float4*)&out[base] = o;
    }
}

// ---------------- launcher ----------------
extern "C" void kernel_launch(void* const* d_in, const int* in_sizes, int n_in,
                              void* d_out, int out_size, void* d_ws, size_t ws_size,
                              hipStream_t stream)
{
    const float* map1  = (const float*)d_in[0];
    const float* map2  = (const float*)d_in[1];
    const float* fm    = (const float*)d_in[2];
    const float* wb    = (const float*)d_in[3];
    const float* bb    = (const float*)d_in[4];
    const float* wc    = (const float*)d_in[5];
    const float* bc    = (const float*)d_in[6];
    const float* wd    = (const float*)d_in[7];
    const float* bd    = (const float*)d_in[8];
    const float* alpha = (const float*)d_in[9];
    float* out = (float*)d_out;

    // ws: featq8 bf16 [4][4096][8] 256KB | featk8 256KB | featd bf16 [4][64][4096] 2MB
    unsigned short* featq8 = (unsigned short*)d_ws;
    unsigned short* featk8 = featq8 + (size_t)BATCH*NSP*8;
    unsigned short* featd  = featk8 + (size_t)BATCH*NSP*8;

    proj_kernel<<<dim3(NSP/64, 2, BATCH), 256, 0, stream>>>(
        map1, map2, fm, wb, bb, wc, bc, wd, bd, featq8, featk8, featd);
    attn_kernel<<<dim3(NSP/TM, 2, BATCH), 256, 0, stream>>>(
        featq8, featk8, featd, fm, alpha, out);
}